// Round 2
// baseline (541.717 us; speedup 1.0000x reference)
//
#include <hip/hip_runtime.h>

typedef unsigned short u16;
typedef unsigned int u32;

typedef __bf16 bfrag __attribute__((ext_vector_type(8)));   // 8 bf16 = 4 VGPRs (MFMA A/B operand)
typedef float f32x4 __attribute__((ext_vector_type(4)));    // MFMA C/D operand

// ---------- bf16 helpers (manual, RNE) ----------
__device__ __forceinline__ float b2f(u16 h) {
    u32 u = ((u32)h) << 16;
    return __builtin_bit_cast(float, u);
}
__device__ __forceinline__ u16 f2b(float f) {
    u32 u = __builtin_bit_cast(u32, f);
    u += 0x7fffu + ((u >> 16) & 1u);
    return (u16)(u >> 16);
}

// Problem constants
#define BATCH 4
#define SEQ   2048
#define DM    1024
#define NH    16
#define HD    64
#define MB    32
#define STOK  (BATCH * SEQ)   // 8192

// ---------- staging helpers: 8 contiguous elements -> 8 bf16 in LDS ----------
__device__ __forceinline__ void stage8(const float* __restrict__ src, u16* dst) {
    float4 a = ((const float4*)src)[0];
    float4 b = ((const float4*)src)[1];
    u16 t[8] = { f2b(a.x), f2b(a.y), f2b(a.z), f2b(a.w),
                 f2b(b.x), f2b(b.y), f2b(b.z), f2b(b.w) };
    *(uint4*)dst = *(uint4*)t;
}
__device__ __forceinline__ void stage8(const u16* __restrict__ src, u16* dst) {
    *(uint4*)dst = *(const uint4*)src;
}

// ---------- epilogue store helpers ----------
__device__ __forceinline__ void storeC(u16* C, size_t idx, float v)   { C[idx] = f2b(v); }
__device__ __forceinline__ void storeC(float* C, size_t idx, float v) { C[idx] = v; }

// =====================================================================
// GEMM: C[M,N] = A[M,K] @ Bt[N,K]^T   (bf16 MFMA, fp32 acc)
// TA in {float, u16}: fp32 A converted to bf16 during LDS staging.
// Bt always fp32 (weights straight from d_in). TC in {u16, float}.
// 128x128 tile, BK=32, 256 thr = 4 waves (2x2), each wave 64x64 (4x4 MFMA tiles)
// =====================================================================
template <typename TA, typename TC>
__global__ __launch_bounds__(256) void gemm_bt(
    const TA* __restrict__ A, const float* __restrict__ Bt, TC* __restrict__ C,
    int M, int Nc, int K)
{
    __shared__ alignas(16) u16 As[128 * 32];
    __shared__ alignas(16) u16 Bs[128 * 32];

    const int tid  = threadIdx.x;
    const int wave = tid >> 6;
    const int lane = tid & 63;
    const int quad = lane >> 4;
    const int lrow = lane & 15;
    const int bm = blockIdx.y * 128;
    const int bn = blockIdx.x * 128;
    const int wm = (wave & 1) * 64;
    const int wn = (wave >> 1) * 64;

    f32x4 acc[4][4] = {};

    for (int k0 = 0; k0 < K; k0 += 32) {
        // stage A-tile and B-tile: 512 chunks of 8 elements each; 2 chunks/tensor/thread
        for (int p = 0; p < 2; ++p) {
            int idx = p * 256 + tid;          // 0..511
            int row = idx >> 2;               // 0..127
            int col = (idx & 3) * 8;          // 0,8,16,24
            stage8(&A [(size_t)(bm + row) * K + k0 + col], &As[row * 32 + col]);
            stage8(&Bt[(size_t)(bn + row) * K + k0 + col], &Bs[row * 32 + col]);
        }
        __syncthreads();

        bfrag af[4], bfv[4];
        for (int i = 0; i < 4; ++i)
            af[i] = *(const bfrag*)&As[(wm + i * 16 + lrow) * 32 + quad * 8];
        for (int j = 0; j < 4; ++j)
            bfv[j] = *(const bfrag*)&Bs[(wn + j * 16 + lrow) * 32 + quad * 8];

        for (int i = 0; i < 4; ++i)
            for (int j = 0; j < 4; ++j)
                acc[i][j] = __builtin_amdgcn_mfma_f32_16x16x32_bf16(af[i], bfv[j], acc[i][j], 0, 0, 0);
        __syncthreads();
    }

    // epilogue: C/D layout col = lane&15, row = quad*4 + r  (m89-verified)
    for (int i = 0; i < 4; ++i)
        for (int j = 0; j < 4; ++j)
            for (int r = 0; r < 4; ++r) {
                int row = bm + wm + i * 16 + quad * 4 + r;
                int col = bn + wn + j * 16 + lrow;
                storeC(C, (size_t)row * Nc + col, acc[i][j][r]);
            }
}

// =====================================================================
// Encode: enc[s,h,m] = tanh( sum_d Qh[s,h,d] * W_enc[h,d,m] )
// Q/K are bf16 workspace; Wenc is fp32 from d_in.
// grid (8192, 2): y=0 -> Q->q_enc, y=1 -> K->k_enc.  512 thr: h=tid>>5, m=tid&31
// =====================================================================
__global__ __launch_bounds__(512) void encode_kernel(
    const u16* __restrict__ Q, const u16* __restrict__ Kmat,
    const float* __restrict__ Wenc,
    u16* __restrict__ qe, u16* __restrict__ ke)
{
    const u16* src = blockIdx.y ? Kmat : Q;
    u16* dst       = blockIdx.y ? ke : qe;
    const int s = blockIdx.x;
    const int h = threadIdx.x >> 5;
    const int m = threadIdx.x & 31;

    __shared__ float xrow[DM];
    for (int i = threadIdx.x; i < DM; i += 512)
        xrow[i] = b2f(src[(size_t)s * DM + i]);
    __syncthreads();

    const float* w = &Wenc[h * (HD * MB) + m];
    const float* xh = &xrow[h * HD];
    float acc = 0.f;
    for (int d = 0; d < HD; ++d)
        acc += xh[d] * w[d * MB];

    // tanh(x) = 1 - 2/(exp(2x)+1): saturates correctly for large |x|
    float e = __expf(2.f * acc);
    float t = 1.f - 2.f / (e + 1.f);
    dst[(size_t)s * (NH * MB) + h * MB + m] = f2b(t);
}

// =====================================================================
// Transpose V [S, 1024] -> Vt [B*H*64, 2048]  (Vt[((b*16+h)*64+d)*2048 + n])
// grid (32, 16, 4), 64x64 tile through LDS
// =====================================================================
__global__ __launch_bounds__(256) void transpose_v(
    const u16* __restrict__ V, u16* __restrict__ Vt)
{
    const int nt = blockIdx.x, h = blockIdx.y, b = blockIdx.z;
    __shared__ alignas(16) u16 tile[64][72];
    const int tid = threadIdx.x;

    for (int p = 0; p < 2; ++p) {
        int idx = p * 256 + tid;          // 0..511
        int t  = idx >> 3;                // token 0..63
        int dc = (idx & 7) * 8;
        *(uint4*)&tile[t][dc] =
            *(const uint4*)&V[(size_t)(b * SEQ + nt * 64 + t) * DM + h * HD + dc];
    }
    __syncthreads();
    for (int p = 0; p < 2; ++p) {
        int idx = p * 256 + tid;
        int d  = idx >> 3;                // 0..63
        int tc = (idx & 7) * 8;
        u16 tmp[8];
        for (int j = 0; j < 8; ++j) tmp[j] = tile[tc + j][d];
        *(uint4*)&Vt[(size_t)((b * NH + h) * HD + d) * SEQ + nt * 64 + tc] = *(uint4*)tmp;
    }
}

// =====================================================================
// Flash attention (no max-subtraction: |scores*scale| <= sqrt(32) ~= 5.66)
// grid (32 qtiles, 16 heads, 4 batch), 256 thr = 4 waves.
// Block owns 64 queries; each wave takes a contiguous 512-key span in 32-key chunks.
// Per chunk: S = q_enc @ k_enc^T (MFMA, K=32 = m_bits), P = exp(S*scale) -> LDS (bf16),
// O += P @ V via MFMA with Vt tile (B-frag rows = d). Cross-wave (num,den) combined in LDS.
// =====================================================================
__global__ __launch_bounds__(256) void flash_attn(
    const u16* __restrict__ qe,   // [S, 512]
    const u16* __restrict__ ke,   // [S, 512]
    const u16* __restrict__ Vt,   // [B*H*64, 2048]
    u16* __restrict__ AO)         // [S, 1024]
{
    const int qt = blockIdx.x, h = blockIdx.y, b = blockIdx.z;
    const int tid  = threadIdx.x;
    const int wave = tid >> 6;
    const int lane = tid & 63;
    const int quad = lane >> 4;
    const int lrow = lane & 15;

    __shared__ float Olds[64 * 64];              // 16 KB
    __shared__ float denlds[4][64];              // 1 KB
    __shared__ alignas(16) u16 Plds[4][64 * 32]; // 16 KB (per-wave P, C->A layout round-trip)
    __shared__ alignas(16) u16 Vlds[4][64 * 32]; // 16 KB (per-wave Vt tile: [d][key])

    const int s0 = b * SEQ + qt * 64;

    // Q fragments: A-layout A[m=lane&15][k=quad*8+j], k spans all 32 m_bits
    bfrag qf[4];
    for (int i = 0; i < 4; ++i)
        qf[i] = *(const bfrag*)&qe[(size_t)(s0 + i * 16 + lrow) * (NH * MB) + h * MB + quad * 8];

    const u16* vtb = &Vt[(size_t)((b * NH + h) * HD) * SEQ];
    u16* myP = Plds[wave];
    u16* myV = Vlds[wave];

    f32x4 O[4][4] = {};
    float den[4][4] = {};
    const float scale = 0.17677669529663687f;   // 1/sqrt(32)

    for (int cc = 0; cc < 16; ++cc) {
        const int k0 = wave * 512 + cc * 32;

        // k_enc fragments (B-operand rows = keys), direct from global
        bfrag kf0 = *(const bfrag*)&ke[(size_t)(b * SEQ + k0 + lrow) * (NH * MB) + h * MB + quad * 8];
        bfrag kf1 = *(const bfrag*)&ke[(size_t)(b * SEQ + k0 + 16 + lrow) * (NH * MB) + h * MB + quad * 8];

        // stage Vt tile [64 d][32 keys] into per-wave LDS
        for (int p = 0; p < 4; ++p) {
            int d  = p * 16 + (lane >> 2);
            int kc = (lane & 3) * 8;
            *(uint4*)&myV[d * 32 + kc] = *(const uint4*)&vtb[(size_t)d * SEQ + k0 + kc];
        }

        // scores: 4 q-tiles x 2 key-tiles
        f32x4 S0[4] = {}, S1[4] = {};
        for (int i = 0; i < 4; ++i) {
            S0[i] = __builtin_amdgcn_mfma_f32_16x16x32_bf16(qf[i], kf0, S0[i], 0, 0, 0);
            S1[i] = __builtin_amdgcn_mfma_f32_16x16x32_bf16(qf[i], kf1, S1[i], 0, 0, 0);
        }

        // P = exp(S*scale); accumulate den; write P to LDS (C-layout: row q = quad*4+r, col key = lrow)
        for (int i = 0; i < 4; ++i)
            for (int r = 0; r < 4; ++r) {
                float e0 = __expf(S0[i][r] * scale);
                float e1 = __expf(S1[i][r] * scale);
                den[i][r] += e0 + e1;
                int q = i * 16 + quad * 4 + r;
                myP[q * 32 + lrow]      = f2b(e0);
                myP[q * 32 + 16 + lrow] = f2b(e1);
            }

        // PV: A-frag = P rows (q), B-frag = Vt rows (d), contraction over 32 keys
        bfrag pf[4], vf[4];
        for (int i = 0; i < 4; ++i)
            pf[i] = *(const bfrag*)&myP[(i * 16 + lrow) * 32 + quad * 8];
        for (int j = 0; j < 4; ++j)
            vf[j] = *(const bfrag*)&myV[(j * 16 + lrow) * 32 + quad * 8];
        for (int i = 0; i < 4; ++i)
            for (int j = 0; j < 4; ++j)
                O[i][j] = __builtin_amdgcn_mfma_f32_16x16x32_bf16(pf[i], vf[j], O[i][j], 0, 0, 0);
    }

    // reduce den across the 16 lanes (lrow) of each quad
    for (int i = 0; i < 4; ++i)
        for (int r = 0; r < 4; ++r) {
            float v = den[i][r];
            v += __shfl_xor(v, 1);
            v += __shfl_xor(v, 2);
            v += __shfl_xor(v, 4);
            v += __shfl_xor(v, 8);
            den[i][r] = v;
        }
    if (lrow == 0)
        for (int i = 0; i < 4; ++i)
            for (int r = 0; r < 4; ++r)
                denlds[wave][i * 16 + quad * 4 + r] = den[i][r];

    // combine O across waves (sequential, deterministic)
    for (int w2 = 0; w2 < 4; ++w2) {
        if (wave == w2) {
            for (int i = 0; i < 4; ++i)
                for (int j = 0; j < 4; ++j)
                    for (int r = 0; r < 4; ++r) {
                        int q = i * 16 + quad * 4 + r;
                        int d = j * 16 + lrow;
                        if (w2 == 0) Olds[q * 64 + d] = O[i][j][r];
                        else         Olds[q * 64 + d] += O[i][j][r];
                    }
        }
        __syncthreads();
    }

    // normalize + store
    for (int idx = tid; idx < 64 * 64; idx += 256) {
        int q = idx >> 6, d = idx & 63;
        float dt = denlds[0][q] + denlds[1][q] + denlds[2][q] + denlds[3][q];
        AO[(size_t)(s0 + q) * DM + h * HD + d] = f2b(Olds[idx] / dt);
    }
}

// =====================================================================
extern "C" void kernel_launch(void* const* d_in, const int* in_sizes, int n_in,
                              void* d_out, int out_size, void* d_ws, size_t ws_size,
                              hipStream_t stream) {
    // Reference dtypes are all float32 (jnp.float32) -> fp32 pointers.
    const float* x    = (const float*)d_in[0];
    const float* Wq   = (const float*)d_in[1];
    const float* Wk   = (const float*)d_in[2];
    const float* Wv   = (const float*)d_in[3];
    const float* Wenc = (const float*)d_in[4];
    const float* Wo   = (const float*)d_in[5];
    float* out = (float*)d_out;

    char* ws = (char*)d_ws;
    u16* Q  = (u16*)(ws);                               // 16 MiB
    u16* K  = (u16*)(ws + (size_t)16 * 1024 * 1024);    // 16 MiB
    u16* V  = (u16*)(ws + (size_t)32 * 1024 * 1024);    // 16 MiB
    u16* qe = (u16*)(ws + (size_t)48 * 1024 * 1024);    // 8 MiB
    u16* ke = (u16*)(ws + (size_t)56 * 1024 * 1024);    // 8 MiB -> 64 MiB total
    u16* Vt = Q;   // alias: Q dead after encode
    u16* AO = K;   // alias: K dead after encode

    dim3 gg(DM / 128, STOK / 128);   // (8, 64)
    gemm_bt<float, u16><<<gg, 256, 0, stream>>>(x, Wq, Q, STOK, DM, DM);
    gemm_bt<float, u16><<<gg, 256, 0, stream>>>(x, Wk, K, STOK, DM, DM);
    gemm_bt<float, u16><<<gg, 256, 0, stream>>>(x, Wv, V, STOK, DM, DM);
    encode_kernel<<<dim3(STOK, 2), 512, 0, stream>>>(Q, K, Wenc, qe, ke);
    transpose_v<<<dim3(SEQ / 64, NH, BATCH), 256, 0, stream>>>(V, Vt);
    flash_attn<<<dim3(SEQ / 64, NH, BATCH), 256, 0, stream>>>(qe, ke, Vt, AO);
    gemm_bt<u16, float><<<gg, 256, 0, stream>>>(AO, Wo, out, STOK, DM, DM);
}

// Round 3
// 423.507 us; speedup vs baseline: 1.2791x; 1.2791x over previous
//
#include <hip/hip_runtime.h>

typedef unsigned short u16;
typedef unsigned int u32;

typedef __bf16 bfrag __attribute__((ext_vector_type(8)));   // 8 bf16 = 4 VGPRs (MFMA A/B operand)
typedef float f32x4 __attribute__((ext_vector_type(4)));    // MFMA C/D operand

// ---------- bf16 helpers ----------
__device__ __forceinline__ float b2f(u16 h) {
    u32 u = ((u32)h) << 16;
    return __builtin_bit_cast(float, u);
}
__device__ __forceinline__ u16 f2b(float f) {   // RNE
    u32 u = __builtin_bit_cast(u32, f);
    u += 0x7fffu + ((u >> 16) & 1u);
    return (u16)(u >> 16);
}
// pack two floats to bf16 pair (round-half-up; fine for attention P weights)
__device__ __forceinline__ u32 pack2(float lo, float hi) {
    u32 a = __builtin_bit_cast(u32, lo) + 0x8000u;
    u32 b = __builtin_bit_cast(u32, hi) + 0x8000u;
    return (a >> 16) | (b & 0xffff0000u);
}

// ---------- fast exp2 ----------
#if defined(__has_builtin)
#if __has_builtin(__builtin_amdgcn_exp2f)
#define EXP2(x) __builtin_amdgcn_exp2f(x)
#endif
#endif
#ifndef EXP2
#define EXP2(x) exp2f(x)
#endif

// ---------- async global->LDS (width 16), with fallback ----------
#if defined(__has_builtin)
#if __has_builtin(__builtin_amdgcn_global_load_lds)
#define HAS_GLL 1
#endif
#endif
#ifndef HAS_GLL
#define HAS_GLL 0
#endif

#if HAS_GLL
typedef __attribute__((address_space(1))) const u32 as1_u32;
typedef __attribute__((address_space(3))) u32 as3_u32;
__device__ __forceinline__ void gl_lds16(const u16* g, u16* l) {
    // lds dest must be wave-uniform; HW stores lane's 16B at base + lane*16
    __builtin_amdgcn_global_load_lds((as1_u32*)g, (as3_u32*)l, 16, 0, 0);
}
#endif

// Problem constants
#define BATCH 4
#define SEQ   2048
#define DM    1024
#define NH    16
#define HD    64
#define MB    32
#define STOK  (BATCH * SEQ)   // 8192

// ---------- epilogue store helpers ----------
__device__ __forceinline__ void storeC(u16* C, size_t idx, float v)   { C[idx] = f2b(v); }
__device__ __forceinline__ void storeC(float* C, size_t idx, float v) { C[idx] = v; }

// =====================================================================
// fp32 -> bf16 conversion kernels (one-shot prepass; memory-bound)
// =====================================================================
__global__ __launch_bounds__(256) void cvt_f32_bf16(
    const float* __restrict__ s, u16* __restrict__ d, int n8)
{
    int i = blockIdx.x * 256 + threadIdx.x;
    if (i >= n8) return;
    const float4* sp = (const float4*)s + (size_t)i * 2;
    float4 a = sp[0], b = sp[1];
    u16 t[8] = { f2b(a.x), f2b(a.y), f2b(a.z), f2b(a.w),
                 f2b(b.x), f2b(b.y), f2b(b.z), f2b(b.w) };
    ((uint4*)d)[i] = *(uint4*)t;
}

__global__ __launch_bounds__(256) void cvt3_f32_bf16(
    const float* __restrict__ a, const float* __restrict__ b,
    const float* __restrict__ c, u16* __restrict__ d, int n8)
{
    const float* s = (blockIdx.y == 0) ? a : ((blockIdx.y == 1) ? b : c);
    u16* dd = d + (size_t)blockIdx.y * n8 * 8;
    int i = blockIdx.x * 256 + threadIdx.x;
    if (i >= n8) return;
    const float4* sp = (const float4*)s + (size_t)i * 2;
    float4 x = sp[0], y = sp[1];
    u16 t[8] = { f2b(x.x), f2b(x.y), f2b(x.z), f2b(x.w),
                 f2b(y.x), f2b(y.y), f2b(y.z), f2b(y.w) };
    ((uint4*)dd)[i] = *(uint4*)t;
}

// =====================================================================
// GEMM: C[M,N] = A[M,K] @ Bt[N,K]^T   (bf16 in, fp32 acc)
// m97-style: 128x128 tile, BK=32, global_load_lds width-16 staging.
// 256 thr = 4 waves (2x2), each wave 64x64 (4x4 MFMA tiles)
// =====================================================================
template <typename TC>
__global__ __launch_bounds__(256) void gemm_bt(
    const u16* __restrict__ A, const u16* __restrict__ Bt, TC* __restrict__ C,
    int M, int Nc, int K)
{
    __shared__ alignas(16) u16 As[128 * 32];
    __shared__ alignas(16) u16 Bs[128 * 32];

    const int tid  = threadIdx.x;
    const int wave = tid >> 6;
    const int lane = tid & 63;
    const int quad = lane >> 4;
    const int lrow = lane & 15;
    const int bm = blockIdx.y * 128;
    const int bn = blockIdx.x * 128;
    const int wm = (wave & 1) * 64;
    const int wn = (wave >> 1) * 64;

    f32x4 acc[4][4] = {};

    for (int k0 = 0; k0 < K; k0 += 32) {
#if HAS_GLL
        // wave w stages A chunks [w*128, w*128+128) and same for B; 16B/lane/inst
        for (int p = 0; p < 2; ++p) {
            int cbase = wave * 128 + p * 64;       // wave-uniform
            int cme   = cbase + lane;              // this lane's 16B chunk
            int row = cme >> 2, col = (cme & 3) * 8;
            gl_lds16(&A [(size_t)(bm + row) * K + k0 + col], &As[(size_t)cbase * 8]);
            gl_lds16(&Bt[(size_t)(bn + row) * K + k0 + col], &Bs[(size_t)cbase * 8]);
        }
#else
        for (int p = 0; p < 2; ++p) {
            int idx = p * 256 + tid, row = idx >> 2, col = (idx & 3) * 8;
            *(uint4*)&As[row * 32 + col] = *(const uint4*)&A [(size_t)(bm + row) * K + k0 + col];
            *(uint4*)&Bs[row * 32 + col] = *(const uint4*)&Bt[(size_t)(bn + row) * K + k0 + col];
        }
#endif
        __syncthreads();   // drains vmcnt(0) -> LDS data visible

        bfrag af[4], bfv[4];
        for (int i = 0; i < 4; ++i)
            af[i] = *(const bfrag*)&As[(wm + i * 16 + lrow) * 32 + quad * 8];
        for (int j = 0; j < 4; ++j)
            bfv[j] = *(const bfrag*)&Bs[(wn + j * 16 + lrow) * 32 + quad * 8];

        for (int i = 0; i < 4; ++i)
            for (int j = 0; j < 4; ++j)
                acc[i][j] = __builtin_amdgcn_mfma_f32_16x16x32_bf16(af[i], bfv[j], acc[i][j], 0, 0, 0);
        __syncthreads();
    }

    // epilogue: C/D layout col = lane&15, row = quad*4 + r (m89-verified)
    for (int i = 0; i < 4; ++i)
        for (int j = 0; j < 4; ++j)
            for (int r = 0; r < 4; ++r) {
                int row = bm + wm + i * 16 + quad * 4 + r;
                int col = bn + wn + j * 16 + lrow;
                storeC(C, (size_t)row * Nc + col, acc[i][j][r]);
            }
}

// =====================================================================
// Encode: enc[s,h,m] = tanh( sum_d Qh[s,h,d] * W_enc[h,d,m] )
// =====================================================================
__global__ __launch_bounds__(512) void encode_kernel(
    const u16* __restrict__ Q, const u16* __restrict__ Kmat,
    const float* __restrict__ Wenc,
    u16* __restrict__ qe, u16* __restrict__ ke)
{
    const u16* src = blockIdx.y ? Kmat : Q;
    u16* dst       = blockIdx.y ? ke : qe;
    const int s = blockIdx.x;
    const int h = threadIdx.x >> 5;
    const int m = threadIdx.x & 31;

    __shared__ float xrow[DM];
    for (int i = threadIdx.x; i < DM; i += 512)
        xrow[i] = b2f(src[(size_t)s * DM + i]);
    __syncthreads();

    const float* w = &Wenc[h * (HD * MB) + m];
    const float* xh = &xrow[h * HD];
    float acc = 0.f;
    for (int d = 0; d < HD; ++d)
        acc += xh[d] * w[d * MB];

    float e = __expf(2.f * acc);
    float t = 1.f - 2.f / (e + 1.f);
    dst[(size_t)s * (NH * MB) + h * MB + m] = f2b(t);
}

// =====================================================================
// Transpose V [S, 1024] -> Vt [B*H*64, 2048]
// =====================================================================
__global__ __launch_bounds__(256) void transpose_v(
    const u16* __restrict__ V, u16* __restrict__ Vt)
{
    const int nt = blockIdx.x, h = blockIdx.y, b = blockIdx.z;
    __shared__ alignas(16) u16 tile[64][72];
    const int tid = threadIdx.x;

    for (int p = 0; p < 2; ++p) {
        int idx = p * 256 + tid;
        int t  = idx >> 3;
        int dc = (idx & 7) * 8;
        *(uint4*)&tile[t][dc] =
            *(const uint4*)&V[(size_t)(b * SEQ + nt * 64 + t) * DM + h * HD + dc];
    }
    __syncthreads();
    for (int p = 0; p < 2; ++p) {
        int idx = p * 256 + tid;
        int d  = idx >> 3;
        int tc = (idx & 7) * 8;
        u16 tmp[8];
        for (int j = 0; j < 8; ++j) tmp[j] = tile[tc + j][d];
        *(uint4*)&Vt[(size_t)((b * NH + h) * HD + d) * SEQ + nt * 64 + tc] = *(uint4*)tmp;
    }
}

// =====================================================================
// Flash attention, S^T formulation.
// grid (h, b, qt) so same-(b,h) blocks co-locate on one XCD (linear%8 = h%8).
// Scores computed transposed: St = k_enc @ q_enc^T, so each lane holds 4
// CONTIGUOUS keys at one q -> P lands in PV A-layout via one ds_write_b64
// per tile (stride 40 u16: write=4cyc min, read b128=8cyc min, no conflicts).
// V fragments loaded DIRECTLY from global Vt (no LDS staging at all).
// No max-subtraction: |s*scale| <= sqrt(32).
// =====================================================================
#define PSTR 40   // P row stride in u16 (80B: 16B-aligned, bank-conflict-free)

__global__ __launch_bounds__(256) void flash_attn(
    const u16* __restrict__ qe,   // [S, 512]
    const u16* __restrict__ ke,   // [S, 512]
    const u16* __restrict__ Vt,   // [B*H*64, 2048]
    u16* __restrict__ AO)         // [S, 1024]
{
    const int h = blockIdx.x, b = blockIdx.y, qt = blockIdx.z;
    const int tid  = threadIdx.x;
    const int wave = tid >> 6;
    const int lane = tid & 63;
    const int quad = lane >> 4;
    const int lrow = lane & 15;

    __shared__ float Olds[64 * 64];               // 16 KB
    __shared__ float denlds[4][64];               // 1 KB
    __shared__ alignas(16) u16 Plds[4][64 * PSTR]; // 20 KB

    const int s0 = b * SEQ + qt * 64;

    // q_enc fragments (B operand now: rows = queries)
    bfrag qf[4];
    for (int i = 0; i < 4; ++i)
        qf[i] = *(const bfrag*)&qe[(size_t)(s0 + i * 16 + lrow) * (NH * MB) + h * MB + quad * 8];

    const u16* vtb = &Vt[(size_t)((b * NH + h) * HD) * SEQ];
    const u16* keb = &ke[(size_t)(b * SEQ) * (NH * MB) + h * MB + quad * 8];
    u16* myP = Plds[wave];

    f32x4 O[4][4] = {};
    float den[4] = {};
    const f32x4 zero = {0.f, 0.f, 0.f, 0.f};
    const float c = 0.25503524337503433f;   // log2(e)/sqrt(32)

    for (int cc = 0; cc < 16; ++cc) {
        const int k0 = wave * 512 + cc * 32;

        // k_enc fragments (A operand: rows = keys)
        bfrag kf0 = *(const bfrag*)&keb[(size_t)(k0 + lrow) * (NH * MB)];
        bfrag kf1 = *(const bfrag*)&keb[(size_t)(k0 + 16 + lrow) * (NH * MB)];
        // V fragments straight from global (B operand: rows = d, k = keys)
        bfrag vf[4];
        for (int j = 0; j < 4; ++j)
            vf[j] = *(const bfrag*)&vtb[(size_t)(j * 16 + lrow) * SEQ + k0 + quad * 8];

        // St[mt][i]: D[key=quad*4+r (+16mt)][q=i*16+lrow]
        f32x4 St[2][4];
        for (int i = 0; i < 4; ++i) {
            St[0][i] = __builtin_amdgcn_mfma_f32_16x16x32_bf16(kf0, qf[i], zero, 0, 0, 0);
            St[1][i] = __builtin_amdgcn_mfma_f32_16x16x32_bf16(kf1, qf[i], zero, 0, 0, 0);
        }

        // P = 2^(St*c): 4 contiguous keys per lane -> one b64 packed LDS write
        for (int mt = 0; mt < 2; ++mt)
            for (int i = 0; i < 4; ++i) {
                float e0 = EXP2(St[mt][i][0] * c);
                float e1 = EXP2(St[mt][i][1] * c);
                float e2 = EXP2(St[mt][i][2] * c);
                float e3 = EXP2(St[mt][i][3] * c);
                den[i] += (e0 + e1) + (e2 + e3);
                uint2 pk = { pack2(e0, e1), pack2(e2, e3) };
                *(uint2*)&myP[(i * 16 + lrow) * PSTR + mt * 16 + quad * 4] = pk;
            }

        // PV: A-frag = P rows (q), B-frag = V rows (d), contraction over 32 keys
        bfrag pf[4];
        for (int i = 0; i < 4; ++i)
            pf[i] = *(const bfrag*)&myP[(i * 16 + lrow) * PSTR + quad * 8];
        for (int i = 0; i < 4; ++i)
            for (int j = 0; j < 4; ++j)
                O[i][j] = __builtin_amdgcn_mfma_f32_16x16x32_bf16(pf[i], vf[j], O[i][j], 0, 0, 0);
    }

    // den: each lane has partial over its keys (quad-strided); reduce across quads
    for (int i = 0; i < 4; ++i) {
        float v = den[i];
        v += __shfl_xor(v, 16);
        v += __shfl_xor(v, 32);
        if (quad == 0) denlds[wave][i * 16 + lrow] = v;
    }

    // combine O across waves (sequential, deterministic)
    for (int w2 = 0; w2 < 4; ++w2) {
        if (wave == w2) {
            for (int i = 0; i < 4; ++i)
                for (int j = 0; j < 4; ++j)
                    for (int r = 0; r < 4; ++r) {
                        int q = i * 16 + quad * 4 + r;
                        int d = j * 16 + lrow;
                        if (w2 == 0) Olds[q * 64 + d] = O[i][j][r];
                        else         Olds[q * 64 + d] += O[i][j][r];
                    }
        }
        __syncthreads();
    }

    // normalize + store
    for (int idx = tid; idx < 64 * 64; idx += 256) {
        int q = idx >> 6, d = idx & 63;
        float dt = denlds[0][q] + denlds[1][q] + denlds[2][q] + denlds[3][q];
        AO[(size_t)(s0 + q) * DM + h * HD + d] = f2b(Olds[idx] / dt);
    }
}

// =====================================================================
extern "C" void kernel_launch(void* const* d_in, const int* in_sizes, int n_in,
                              void* d_out, int out_size, void* d_ws, size_t ws_size,
                              hipStream_t stream) {
    const float* x    = (const float*)d_in[0];
    const float* Wq   = (const float*)d_in[1];
    const float* Wk   = (const float*)d_in[2];
    const float* Wv   = (const float*)d_in[3];
    const float* Wenc = (const float*)d_in[4];
    const float* Wo   = (const float*)d_in[5];
    float* out = (float*)d_out;

    const size_t MB16 = (size_t)16 * 1024 * 1024;
    char* ws = (char*)d_ws;
    u16* Q  = (u16*)(ws);             // R0: Q, later Vt
    u16* K  = (u16*)(ws + MB16);      // R1: K, later AO
    u16* V  = (u16*)(ws + 2 * MB16);  // R2: V, later Wo_b
    u16* qe = (u16*)(ws + 3 * MB16);                    // 8 MiB
    u16* ke = (u16*)(ws + 3 * MB16 + MB16 / 2);         // 8 MiB -> 64 MiB total
    u16* Vt = Q;
    u16* AO = K;
    u16* Wo_b = V;                    // V dead after transpose

    // d_out (32 MiB fp32) doubles as prepass scratch; dead before final GEMM.
    u16* xb   = (u16*)d_out;                            // 16 MiB bf16 x
    u16* w3b  = (u16*)((char*)d_out + MB16);            // 6 MiB: Wq_b,Wk_b,Wv_b
    u16* Wq_b = w3b;
    u16* Wk_b = w3b + (size_t)DM * DM;
    u16* Wv_b = w3b + (size_t)2 * DM * DM;

    dim3 gg(DM / 128, STOK / 128);   // (8, 64)

    cvt_f32_bf16<<<dim3((STOK * DM / 8 + 255) / 256), 256, 0, stream>>>(x, xb, STOK * DM / 8);
    cvt3_f32_bf16<<<dim3((DM * DM / 8 + 255) / 256, 3), 256, 0, stream>>>(Wq, Wk, Wv, w3b, DM * DM / 8);

    gemm_bt<u16><<<gg, 256, 0, stream>>>(xb, Wq_b, Q, STOK, DM, DM);
    gemm_bt<u16><<<gg, 256, 0, stream>>>(xb, Wk_b, K, STOK, DM, DM);
    gemm_bt<u16><<<gg, 256, 0, stream>>>(xb, Wv_b, V, STOK, DM, DM);

    encode_kernel<<<dim3(STOK, 2), 512, 0, stream>>>(Q, K, Wenc, qe, ke);
    transpose_v<<<dim3(SEQ / 64, NH, BATCH), 256, 0, stream>>>(V, Vt);
    cvt_f32_bf16<<<dim3((DM * DM / 8 + 255) / 256), 256, 0, stream>>>(Wo, Wo_b, DM * DM / 8);

    flash_attn<<<dim3(NH, BATCH, SEQ / 64), 256, 0, stream>>>(qe, ke, Vt, AO);

    gemm_bt<float><<<gg, 256, 0, stream>>>(AO, Wo_b, out, STOK, DM, DM);
}